// Round 3
// baseline (298.993 us; speedup 1.0000x reference)
//
#include <hip/hip_runtime.h>

#define B_DIM 64
#define T_DIM 524288
#define D_FAC 16
#define NF 32768         // frames per row (T/D)
#define LBLK 64          // frames per level-0 block
#define NB64 512         // 64-frame blocks per row
#define NCLS 65          // classes in a 64-frame map
#define NB256 128        // 256-frame superblocks per row
#define NC2 257          // classes in a 256-frame map
#define EPSV 1e-7f
#define BIGC 1e30f

// 20*log10(2)
#define DB_PER_LOG2 6.0205999132796239f
// log2(10)/20
#define L2TEN_OVER20 0.16609640474436813f

__device__ __forceinline__ float sum_log2_4(float4 x) {
  return __log2f(fabsf(x.x) + EPSV) + __log2f(fabsf(x.y) + EPSV) +
         __log2f(fabsf(x.z) + EPSV) + __log2f(fabsf(x.w) + EPSV);
}

template <int CTRL, int RM>
__device__ __forceinline__ float fmin_dpp_step(float v) {
  int vi = __float_as_int(v);
  int sh = __builtin_amdgcn_update_dpp(vi, vi, CTRL, RM, 0xf, false);
  return fminf(v, __int_as_float(sh));
}

// K1: per-frame gain g, DP-compose each 64-frame block into a 65-class map.
__global__ __launch_bounds__(256) void k1_compose(
    const float* __restrict__ audio, const float* __restrict__ p_thr,
    const float* __restrict__ p_ratio, const float* __restrict__ p_att,
    const float* __restrict__ p_rel, float* __restrict__ maps64) {
  __shared__ float gl[4096 + 128];
  const int tid = threadIdx.x;
  const int wg = blockIdx.x;  // 0..511
  const int row = wg >> 3;
  const int seg = wg & 7;
  const float thr = p_thr[0];
  const float ratio = p_ratio[0];
  const float A = p_att[0], R = p_rel[0];
  const float oneA = 1.f - A, oneR = 1.f - R;
  const float gslope = (1.f / ratio) - 1.f;
  const size_t abase = (size_t)row * T_DIM + (size_t)seg * (4096 * D_FAC);

  for (int j = 0; j < 16; ++j) {
    int f = j * 256 + tid;
    const float4* ap = (const float4*)(audio + abase + (size_t)f * D_FAC);
    float s = 0.f;
#pragma unroll
    for (int q = 0; q < 4; ++q) s += sum_log2_4(ap[q]);
    float xdb = s * (DB_PER_LOG2 / 16.f);
    float g = fminf(0.f, (xdb - thr) * gslope);
    gl[f + (f >> 5)] = g;
  }
  __syncthreads();
  if (tid >= 64) return;

  float c[NCLS];
  c[0] = 0.f;
#pragma unroll
  for (int a = 1; a < NCLS; ++a) c[a] = BIGC;
  const int ebase = tid * LBLK;
  for (int t = 0; t < LBLK; ++t) {
    int e = ebase + t;
    float gt = gl[e + (e >> 5)];
    float ca = oneA * gt, cr = oneR * gt;
#pragma unroll
    for (int a = NCLS - 1; a >= 1; --a)
      c[a] = fminf(fmaf(A, c[a - 1], ca), fmaf(R, c[a], cr));
    c[0] = fmaf(R, c[0], cr);
  }
  float* outp = maps64 + (size_t)(row * NB64 + seg * 64 + tid) * NCLS;
#pragma unroll
  for (int a = 0; a < NCLS; ++a) outp[a] = c[a];
}

// K1b: compose 4 consecutive 64-maps -> one 256-map (two levels, fused in LDS).
// c_out[k] = min_{a2} ( S2[a2]*c_first[k-a2] + c_second[a2] )
__global__ __launch_bounds__(256) void k1b_compose(
    const float* __restrict__ maps64, const float* __restrict__ p_att,
    const float* __restrict__ p_rel, float* __restrict__ maps256) {
  __shared__ float m64f[260];   // 4 x 65
  __shared__ float m128f[258];  // 2 x 129
  __shared__ float s64t[65];
  __shared__ float s128t[129];
  const int t = threadIdx.x;
  const int sb = blockIdx.x;  // row*128 + blk4
  const float A = p_att[0], R = p_rel[0];
  const float l2A = __log2f(A), l2R = __log2f(R);

  const float* src = maps64 + (size_t)sb * 4 * NCLS;
  m64f[t] = src[t];
  if (t < 4) m64f[256 + t] = src[256 + t];
  if (t < 65) s64t[t] = exp2f((float)t * l2A + (float)(64 - t) * l2R);
  if (t < 129) s128t[t] = exp2f((float)t * l2A + (float)(128 - t) * l2R);
  __syncthreads();

  // level 1: two compositions (blocks 0+1 -> m128[0], blocks 2+3 -> m128[1])
  for (int i = t; i < 258; i += 256) {
    int c = (i >= 129) ? 1 : 0;
    int k = i - c * 129;
    const float* f1 = m64f + c * 130;
    const float* f2 = f1 + 65;
    float acc = BIGC;
    for (int a2 = 0; a2 <= 64; ++a2) {
      int idx = k - a2;
      int ci = idx < 0 ? 0 : (idx > 64 ? 64 : idx);
      float v = fmaf(s64t[a2], f1[ci], f2[a2]);
      acc = (idx >= 0 && idx <= 64) ? fminf(acc, v) : acc;
    }
    m128f[c * 129 + k] = acc;
  }
  __syncthreads();

  // level 2: m128[0] (earlier) composed with m128[1] (later) -> 257 classes
  float* outp = maps256 + (size_t)sb * NC2;
  for (int k = t; k < NC2; k += 256) {
    float acc = BIGC;
    for (int a2 = 0; a2 <= 128; ++a2) {
      int idx = k - a2;
      int ci = idx < 0 ? 0 : (idx > 128 ? 128 : idx);
      float v = fmaf(s128t[a2], m128f[ci], m128f[129 + a2]);
      acc = (idx >= 0 && idx <= 128) ? fminf(acc, v) : acc;
    }
    outp[k] = acc;
  }
}

// K2: serial scan over 128 superblocks per row. One wave per row; lane l
// holds classes {l, l+64, l+128, l+192} (+ class 256 on lane 0).
__global__ __launch_bounds__(64) void k2_scan(const float* __restrict__ maps256,
                                              float* __restrict__ states,
                                              const float* __restrict__ p_att,
                                              const float* __restrict__ p_rel) {
  const int r = blockIdx.x;
  const int lane = threadIdx.x;
  const float A = p_att[0], R = p_rel[0];
  const float l2A = __log2f(A), l2R = __log2f(R);
  float sl[5];
#pragma unroll
  for (int j = 0; j < 4; ++j) {
    float a = (float)(lane + 64 * j);
    sl[j] = exp2f(a * l2A + (256.f - a) * l2R);
  }
  sl[4] = (lane == 0) ? exp2f(256.f * l2A) : 1.f;

  const float* base = maps256 + (size_t)r * NB256 * NC2;
  float* st = states + r * NB256;
  float p = 0.f;

  float cb[4][5];
#pragma unroll
  for (int d = 0; d < 4; ++d) {
#pragma unroll
    for (int j = 0; j < 4; ++j) cb[d][j] = base[d * NC2 + lane + 64 * j];
    float extra = base[d * NC2 + 256];
    cb[d][4] = (lane == 0) ? extra : BIGC;
  }
  for (int b = 0; b < NB256; ++b) {
    int d = b & 3;
    float f0 = fmaf(sl[0], p, cb[d][0]);
    float f1 = fmaf(sl[1], p, cb[d][1]);
    float f2 = fmaf(sl[2], p, cb[d][2]);
    float f3 = fmaf(sl[3], p, cb[d][3]);
    float f4 = fmaf(sl[4], p, cb[d][4]);
    float v = fminf(fminf(fminf(f0, f1), fminf(f2, f3)), f4);
    v = fmin_dpp_step<0x111, 0xf>(v);  // row_shr:1
    v = fmin_dpp_step<0x112, 0xf>(v);  // row_shr:2
    v = fmin_dpp_step<0x114, 0xf>(v);  // row_shr:4
    v = fmin_dpp_step<0x118, 0xf>(v);  // row_shr:8
    v = fmin_dpp_step<0x142, 0xa>(v);  // row_bcast:15
    v = fmin_dpp_step<0x143, 0xc>(v);  // row_bcast:31
    if (lane == 0) st[b] = p;          // state at START of superblock b
    p = __int_as_float(__builtin_amdgcn_readlane(__float_as_int(v), 63));
    int nb = b + 4;
    if (nb < NB256) {
#pragma unroll
      for (int j = 0; j < 4; ++j) cb[d][j] = base[nb * NC2 + lane + 64 * j];
      float extra = base[nb * NC2 + 256];
      cb[d][4] = (lane == 0) ? extra : BIGC;
    }
  }
}

// K3: one wave per 256-frame superblock; 4 sub-blocks of 64 frames done
// sequentially, carrying the envelope state p exactly.
__global__ __launch_bounds__(256) void k3_apply(
    const float* __restrict__ audio, const float* __restrict__ states,
    const float* __restrict__ p_thr, const float* __restrict__ p_ratio,
    const float* __restrict__ p_makeup, const float* __restrict__ p_att,
    const float* __restrict__ p_rel, float* __restrict__ out) {
  const int tid = threadIdx.x;
  const int lane = tid & 63;
  const int w = tid >> 6;
  const int sb = blockIdx.x * 4 + w;  // 0..8191
  const int row = sb >> 7;
  const int b4 = sb & (NB256 - 1);
  const float thr = p_thr[0], ratio = p_ratio[0], mk = p_makeup[0];
  const float A = p_att[0], R = p_rel[0];
  const float oneA = 1.f - A, oneR = 1.f - R;
  const float gslope = (1.f / ratio) - 1.f;
  const size_t rowbase = (size_t)row * T_DIM;

  float p = states[sb];
  for (int sub = 0; sub < 4; ++sub) {
    const int frame = b4 * 256 + sub * 64 + lane;
    const size_t sbase = rowbase + (size_t)frame * D_FAC;
    const float4* ap = (const float4*)(audio + sbase);
    float4 x0 = ap[0], x1 = ap[1], x2 = ap[2], x3 = ap[3];
    float s = sum_log2_4(x0) + sum_log2_4(x1) + sum_log2_4(x2) + sum_log2_4(x3);
    float xdb = s * (DB_PER_LOG2 / 16.f);
    float g = fminf(0.f, (xdb - thr) * gslope);

    float m = 0.f;
    int gi = __float_as_int(g);
#pragma unroll
    for (int t = 0; t < LBLK; ++t) {
      float gt = __int_as_float(__builtin_amdgcn_readlane(gi, t));
      p = fminf(fmaf(A, p, oneA * gt), fmaf(R, p, oneR * gt));
      m = (lane == t) ? p : m;
    }
    float mult = exp2f((m + mk) * L2TEN_OVER20);
    float4* op = (float4*)(out + sbase);
    float4 y0, y1, y2, y3;
    y0.x = x0.x * mult; y0.y = x0.y * mult; y0.z = x0.z * mult; y0.w = x0.w * mult;
    y1.x = x1.x * mult; y1.y = x1.y * mult; y1.z = x1.z * mult; y1.w = x1.w * mult;
    y2.x = x2.x * mult; y2.y = x2.y * mult; y2.z = x2.z * mult; y2.w = x2.w * mult;
    y3.x = x3.x * mult; y3.y = x3.y * mult; y3.z = x3.z * mult; y3.w = x3.w * mult;
    op[0] = y0; op[1] = y1; op[2] = y2; op[3] = y3;
  }
}

extern "C" void kernel_launch(void* const* d_in, const int* in_sizes, int n_in,
                              void* d_out, int out_size, void* d_ws,
                              size_t ws_size, hipStream_t stream) {
  const float* audio = (const float*)d_in[0];
  const float* thr = (const float*)d_in[1];
  const float* ratio = (const float*)d_in[2];
  const float* makeup = (const float*)d_in[3];
  const float* att = (const float*)d_in[4];
  const float* rel = (const float*)d_in[5];
  float* out = (float*)d_out;

  const size_t MAPS64_BYTES = (size_t)B_DIM * NB64 * NCLS * sizeof(float);   // ~8.5 MB
  const size_t MAPS256_BYTES = (size_t)B_DIM * NB256 * NC2 * sizeof(float);  // ~8.4 MB
  const size_t STATES_BYTES = (size_t)B_DIM * NB256 * sizeof(float);         // 32 KB

  float* maps64;
  float* maps256;
  float* states;
  if (ws_size >= MAPS64_BYTES + MAPS256_BYTES + STATES_BYTES) {
    maps64 = (float*)d_ws;
    maps256 = (float*)((char*)d_ws + MAPS64_BYTES);
    states = (float*)((char*)d_ws + MAPS64_BYTES + MAPS256_BYTES);
  } else {
    // d_out as scratch for the maps (dead before K3 runs; K3 overwrites all
    // of d_out). states stays in d_ws (32 KB; round-2 proved ws >= 128 KB).
    maps64 = (float*)d_out;
    maps256 = (float*)((char*)d_out + MAPS64_BYTES);
    states = (float*)d_ws;
  }

  hipLaunchKernelGGL(k1_compose, dim3(512), dim3(256), 0, stream, audio, thr,
                     ratio, att, rel, maps64);
  hipLaunchKernelGGL(k1b_compose, dim3(8192), dim3(256), 0, stream, maps64,
                     att, rel, maps256);
  hipLaunchKernelGGL(k2_scan, dim3(64), dim3(64), 0, stream, maps256, states,
                     att, rel);
  hipLaunchKernelGGL(k3_apply, dim3(2048), dim3(256), 0, stream, audio, states,
                     thr, ratio, makeup, att, rel, out);
}

// Round 4
// 152.406 us; speedup vs baseline: 1.9618x; 1.9618x over previous
//
#include <hip/hip_runtime.h>

#define B_DIM 64
#define T_DIM 524288
#define D_FAC 16
#define NF 32768         // frames per row (T/D)
#define LBLK 64          // frames per composed block
#define NB 512           // blocks per row
#define NCLS 65          // LBLK+1 slope classes
#define PF 16            // K2 prefetch depth (blocks)
#define EPSV 1e-7f
#define BIGC 1e30f

// 20*log10(2)
#define DB_PER_LOG2 6.0205999132796239f
// log2(10)/20
#define L2TEN_OVER20 0.16609640474436813f

__device__ __forceinline__ float sum_log2_4(float4 x) {
  return __log2f(fabsf(x.x) + EPSV) + __log2f(fabsf(x.y) + EPSV) +
         __log2f(fabsf(x.z) + EPSV) + __log2f(fabsf(x.w) + EPSV);
}

template <int CTRL, int RM>
__device__ __forceinline__ float fmin_dpp_step(float v) {
  int vi = __float_as_int(v);
  int sh = __builtin_amdgcn_update_dpp(vi, vi, CTRL, RM, 0xf, false);
  return fminf(v, __int_as_float(sh));
}

// K1: per-frame gain g, DP-compose each 64-frame block into a 65-class
// min-affine map. One WG = 256 threads covers 4096 frames.
__global__ __launch_bounds__(256) void k1_compose(
    const float* __restrict__ audio, const float* __restrict__ p_thr,
    const float* __restrict__ p_ratio, const float* __restrict__ p_att,
    const float* __restrict__ p_rel, float* __restrict__ consts) {
  __shared__ float gl[4096 + 128];  // pad 1 float per 32
  const int tid = threadIdx.x;
  const int wg = blockIdx.x;  // 0..511
  const int row = wg >> 3;
  const int seg = wg & 7;
  const float thr = p_thr[0];
  const float ratio = p_ratio[0];
  const float A = p_att[0], R = p_rel[0];
  const float oneA = 1.f - A, oneR = 1.f - R;
  const float gslope = (1.f / ratio) - 1.f;
  const size_t abase = (size_t)row * T_DIM + (size_t)seg * (4096 * D_FAC);

  for (int j = 0; j < 16; ++j) {
    int f = j * 256 + tid;
    const float4* ap = (const float4*)(audio + abase + (size_t)f * D_FAC);
    float s = 0.f;
#pragma unroll
    for (int q = 0; q < 4; ++q) s += sum_log2_4(ap[q]);
    float xdb = s * (DB_PER_LOG2 / 16.f);
    float g = fminf(0.f, (xdb - thr) * gslope);
    gl[f + (f >> 5)] = g;
  }
  __syncthreads();
  if (tid >= 64) return;

  float c[NCLS];
  c[0] = 0.f;
#pragma unroll
  for (int a = 1; a < NCLS; ++a) c[a] = BIGC;
  const int ebase = tid * LBLK;
  for (int t = 0; t < LBLK; ++t) {
    int e = ebase + t;
    float gt = gl[e + (e >> 5)];
    float ca = oneA * gt, cr = oneR * gt;
#pragma unroll
    for (int a = NCLS - 1; a >= 1; --a)
      c[a] = fminf(fmaf(A, c[a - 1], ca), fmaf(R, c[a], cr));
    c[0] = fmaf(R, c[0], cr);
  }
  float* outp = consts + (size_t)(row * NB + seg * 64 + tid) * NCLS;
#pragma unroll
  for (int a = 0; a < NCLS; ++a) outp[a] = c[a];
}

// K2: serial scan over 512 blocks per row. One wave per row; lane a holds
// slope class a (lane 63 also class 64). 16-deep register prefetch, no
// in-loop stores (states kept in regs, written at 64-step group ends).
__global__ __launch_bounds__(64) void k2_scan(const float* __restrict__ consts,
                                              float* __restrict__ states,
                                              const float* __restrict__ p_att,
                                              const float* __restrict__ p_rel) {
  const int r = blockIdx.x;
  const int lane = threadIdx.x;
  const float A = p_att[0], R = p_rel[0];
  float s = 1.f, sA = 1.f;
  for (int i = 0; i < 64; ++i) {
    s *= (i < lane) ? A : R;  // s = A^lane * R^(64-lane)
    sA *= A;                  // A^64
  }
  const bool last = (lane == 63);
  const float s2 = last ? sA : s;
  const int off1 = lane;
  const int off2 = last ? 64 : lane;
  const float* base = consts + (size_t)r * NB * NCLS;
  float* st = states + r * NB;
  float p = 0.f;

  float cb[PF], eb[PF];
#pragma unroll
  for (int u = 0; u < PF; ++u) {
    cb[u] = base[u * NCLS + off1];
    eb[u] = base[u * NCLS + off2];
  }

  for (int j = 0; j < 8; ++j) {       // 8 groups of 64 steps
    float sj = 0.f;                   // state slot: lane i holds block j*64+i
    for (int k = 0; k < 4; ++k) {     // 4 sub-groups of 16
#pragma unroll
      for (int u = 0; u < PF; ++u) {  // circular prefetch slot = u
        const int b = j * 64 + k * PF + u;
        const int i = k * PF + u;  // step within group (uniform)
        float f = fmaf(s, p, cb[u]);
        float e = fmaf(s2, p, eb[u]);
        float v = fminf(f, e);
        v = fmin_dpp_step<0x111, 0xf>(v);  // row_shr:1
        v = fmin_dpp_step<0x112, 0xf>(v);  // row_shr:2
        v = fmin_dpp_step<0x114, 0xf>(v);  // row_shr:4
        v = fmin_dpp_step<0x118, 0xf>(v);  // row_shr:8
        v = fmin_dpp_step<0x142, 0xa>(v);  // row_bcast:15
        v = fmin_dpp_step<0x143, 0xc>(v);  // row_bcast:31
        sj = (lane == i) ? p : sj;  // state at START of block b (old p)
        p = __int_as_float(
            __builtin_amdgcn_readlane(__float_as_int(v), 63));
        // refill slot u for block b+PF (buffer padded; no tail branch)
        cb[u] = base[(b + PF) * NCLS + off1];
        eb[u] = base[(b + PF) * NCLS + off2];
      }
    }
    st[j * 64 + lane] = sj;
  }
}

// K3: one wave per block. Each lane owns one frame (16 samples in regs),
// wave re-runs the 64-step recurrence from the block-start state via
// readlane broadcasts, then applies gain.
__global__ __launch_bounds__(256) void k3_apply(
    const float* __restrict__ audio, const float* __restrict__ states,
    const float* __restrict__ p_thr, const float* __restrict__ p_ratio,
    const float* __restrict__ p_makeup, const float* __restrict__ p_att,
    const float* __restrict__ p_rel, float* __restrict__ out) {
  const int tid = threadIdx.x;
  const int lane = tid & 63;
  const int w = tid >> 6;
  const int gblk = blockIdx.x * 4 + w;  // 0..32767
  const int row = gblk >> 9;
  const int b = gblk & (NB - 1);
  const float thr = p_thr[0], ratio = p_ratio[0], mk = p_makeup[0];
  const float A = p_att[0], R = p_rel[0];
  const float oneA = 1.f - A, oneR = 1.f - R;
  const float gslope = (1.f / ratio) - 1.f;

  const size_t sbase = (size_t)row * T_DIM + (size_t)(b * LBLK + lane) * D_FAC;
  const float4* ap = (const float4*)(audio + sbase);
  float4 x0 = ap[0], x1 = ap[1], x2 = ap[2], x3 = ap[3];
  float s = sum_log2_4(x0) + sum_log2_4(x1) + sum_log2_4(x2) + sum_log2_4(x3);
  float xdb = s * (DB_PER_LOG2 / 16.f);
  float g = fminf(0.f, (xdb - thr) * gslope);

  float p = states[gblk];
  float m = 0.f;
  int gi = __float_as_int(g);
#pragma unroll
  for (int t = 0; t < LBLK; ++t) {
    float gt = __int_as_float(__builtin_amdgcn_readlane(gi, t));
    p = fminf(fmaf(A, p, oneA * gt), fmaf(R, p, oneR * gt));
    m = (lane == t) ? p : m;
  }
  float mult = exp2f((m + mk) * L2TEN_OVER20);
  float4* op = (float4*)(out + sbase);
  float4 y0, y1, y2, y3;
  y0.x = x0.x * mult; y0.y = x0.y * mult; y0.z = x0.z * mult; y0.w = x0.w * mult;
  y1.x = x1.x * mult; y1.y = x1.y * mult; y1.z = x1.z * mult; y1.w = x1.w * mult;
  y2.x = x2.x * mult; y2.y = x2.y * mult; y2.z = x2.z * mult; y2.w = x2.w * mult;
  y3.x = x3.x * mult; y3.y = x3.y * mult; y3.z = x3.z * mult; y3.w = x3.w * mult;
  op[0] = y0; op[1] = y1; op[2] = y2; op[3] = y3;
}

extern "C" void kernel_launch(void* const* d_in, const int* in_sizes, int n_in,
                              void* d_out, int out_size, void* d_ws,
                              size_t ws_size, hipStream_t stream) {
  const float* audio = (const float*)d_in[0];
  const float* thr = (const float*)d_in[1];
  const float* ratio = (const float*)d_in[2];
  const float* makeup = (const float*)d_in[3];
  const float* att = (const float*)d_in[4];
  const float* rel = (const float*)d_in[5];
  float* out = (float*)d_out;

  const size_t CONSTS_BYTES = (size_t)B_DIM * NB * NCLS * sizeof(float);  // ~8.5 MB
  const size_t PAD_BYTES = (size_t)PF * NCLS * sizeof(float);             // tail prefetch pad
  const size_t STATES_BYTES = (size_t)B_DIM * NB * sizeof(float);         // 128 KB

  float* consts;
  float* states;
  if (ws_size >= CONSTS_BYTES + PAD_BYTES + STATES_BYTES) {
    consts = (float*)d_ws;
    states = (float*)((char*)d_ws + CONSTS_BYTES + PAD_BYTES);
  } else {
    // d_out (128 MB) as scratch for consts: only live during K1->K2, and K3
    // overwrites every byte of d_out afterwards. states (128 KB) in ws.
    consts = (float*)d_out;
    states = (float*)d_ws;
  }

  hipLaunchKernelGGL(k1_compose, dim3(512), dim3(256), 0, stream, audio, thr,
                     ratio, att, rel, consts);
  hipLaunchKernelGGL(k2_scan, dim3(64), dim3(64), 0, stream, consts, states,
                     att, rel);
  hipLaunchKernelGGL(k3_apply, dim3(8192), dim3(256), 0, stream, audio, states,
                     thr, ratio, makeup, att, rel, out);
}

// Round 5
// 152.118 us; speedup vs baseline: 1.9655x; 1.0019x over previous
//
#include <hip/hip_runtime.h>

#define B_DIM 64
#define T_DIM 524288
#define D_FAC 16
#define NF 32768         // frames per row (T/D)
#define LBLK 64          // frames per composed block
#define NB 512           // blocks per row
#define NCLS 65          // LBLK+1 slope classes
#define PF 16            // K2 prefetch depth (blocks)
#define EPSV 1e-7f
#define BIGC 1e30f

// 20*log10(2)
#define DB_PER_LOG2 6.0205999132796239f
// log2(10)/20
#define L2TEN_OVER20 0.16609640474436813f

__device__ __forceinline__ float sum_log2_4(float4 x) {
  return __log2f(fabsf(x.x) + EPSV) + __log2f(fabsf(x.y) + EPSV) +
         __log2f(fabsf(x.z) + EPSV) + __log2f(fabsf(x.w) + EPSV);
}

template <int CTRL, int RM>
__device__ __forceinline__ float fmin_dpp_step(float v) {
  int vi = __float_as_int(v);
  int sh = __builtin_amdgcn_update_dpp(vi, vi, CTRL, RM, 0xf, false);
  return fminf(v, __int_as_float(sh));
}

// K1: per-frame gain g, DP-compose each 64-frame block into a 65-class
// min-affine map. DP state in 65 NAMED scalars (VGPR_Count=40 in r4 proved
// the c[65] array was demoted to scratch; named scalars force registers).
__global__ __launch_bounds__(256, 1) void k1_compose(
    const float* __restrict__ audio, const float* __restrict__ p_thr,
    const float* __restrict__ p_ratio, const float* __restrict__ p_att,
    const float* __restrict__ p_rel, float* __restrict__ consts) {
  __shared__ float gl[4096 + 128];  // pad 1 float per 32
  const int tid = threadIdx.x;
  const int wg = blockIdx.x;  // 0..511
  const int row = wg >> 3;
  const int seg = wg & 7;
  const float thr = p_thr[0];
  const float ratio = p_ratio[0];
  const float A = p_att[0], R = p_rel[0];
  const float oneA = 1.f - A, oneR = 1.f - R;
  const float gslope = (1.f / ratio) - 1.f;
  const size_t abase = (size_t)row * T_DIM + (size_t)seg * (4096 * D_FAC);

  for (int j = 0; j < 16; ++j) {
    int f = j * 256 + tid;
    const float4* ap = (const float4*)(audio + abase + (size_t)f * D_FAC);
    float s = 0.f;
#pragma unroll
    for (int q = 0; q < 4; ++q) s += sum_log2_4(ap[q]);
    float xdb = s * (DB_PER_LOG2 / 16.f);
    float g = fminf(0.f, (xdb - thr) * gslope);
    gl[f + (f >> 5)] = g;
  }
  __syncthreads();
  if (tid >= 64) return;

  float c0 = 0.f;
  float c1 = BIGC, c2 = BIGC, c3 = BIGC, c4 = BIGC, c5 = BIGC, c6 = BIGC,
        c7 = BIGC, c8 = BIGC, c9 = BIGC, c10 = BIGC, c11 = BIGC, c12 = BIGC,
        c13 = BIGC, c14 = BIGC, c15 = BIGC, c16 = BIGC, c17 = BIGC,
        c18 = BIGC, c19 = BIGC, c20 = BIGC, c21 = BIGC, c22 = BIGC,
        c23 = BIGC, c24 = BIGC, c25 = BIGC, c26 = BIGC, c27 = BIGC,
        c28 = BIGC, c29 = BIGC, c30 = BIGC, c31 = BIGC, c32 = BIGC,
        c33 = BIGC, c34 = BIGC, c35 = BIGC, c36 = BIGC, c37 = BIGC,
        c38 = BIGC, c39 = BIGC, c40 = BIGC, c41 = BIGC, c42 = BIGC,
        c43 = BIGC, c44 = BIGC, c45 = BIGC, c46 = BIGC, c47 = BIGC,
        c48 = BIGC, c49 = BIGC, c50 = BIGC, c51 = BIGC, c52 = BIGC,
        c53 = BIGC, c54 = BIGC, c55 = BIGC, c56 = BIGC, c57 = BIGC,
        c58 = BIGC, c59 = BIGC, c60 = BIGC, c61 = BIGC, c62 = BIGC,
        c63 = BIGC, c64 = BIGC;
  const int ebase = tid * LBLK;
#pragma unroll 1
  for (int t = 0; t < LBLK; ++t) {
    int e = ebase + t;
    float gt = gl[e + (e >> 5)];
    float ca = oneA * gt, cr = oneR * gt;
#define U(a, b) c##a = fminf(fmaf(A, c##b, ca), fmaf(R, c##a, cr));
    U(64, 63) U(63, 62) U(62, 61) U(61, 60) U(60, 59) U(59, 58) U(58, 57)
    U(57, 56) U(56, 55) U(55, 54) U(54, 53) U(53, 52) U(52, 51) U(51, 50)
    U(50, 49) U(49, 48) U(48, 47) U(47, 46) U(46, 45) U(45, 44) U(44, 43)
    U(43, 42) U(42, 41) U(41, 40) U(40, 39) U(39, 38) U(38, 37) U(37, 36)
    U(36, 35) U(35, 34) U(34, 33) U(33, 32) U(32, 31) U(31, 30) U(30, 29)
    U(29, 28) U(28, 27) U(27, 26) U(26, 25) U(25, 24) U(24, 23) U(23, 22)
    U(22, 21) U(21, 20) U(20, 19) U(19, 18) U(18, 17) U(17, 16) U(16, 15)
    U(15, 14) U(14, 13) U(13, 12) U(12, 11) U(11, 10) U(10, 9) U(9, 8)
    U(8, 7) U(7, 6) U(6, 5) U(5, 4) U(4, 3) U(3, 2) U(2, 1) U(1, 0)
#undef U
    c0 = fmaf(R, c0, cr);
  }
  float* outp = consts + (size_t)(row * NB + seg * 64 + tid) * NCLS;
#define S(a) outp[a] = c##a;
  S(0) S(1) S(2) S(3) S(4) S(5) S(6) S(7) S(8) S(9) S(10) S(11) S(12) S(13)
  S(14) S(15) S(16) S(17) S(18) S(19) S(20) S(21) S(22) S(23) S(24) S(25)
  S(26) S(27) S(28) S(29) S(30) S(31) S(32) S(33) S(34) S(35) S(36) S(37)
  S(38) S(39) S(40) S(41) S(42) S(43) S(44) S(45) S(46) S(47) S(48) S(49)
  S(50) S(51) S(52) S(53) S(54) S(55) S(56) S(57) S(58) S(59) S(60) S(61)
  S(62) S(63) S(64)
#undef S
}

// K2: serial scan over 512 blocks per row. One wave per row; lane a holds
// slope class a (lane 63 also class 64). 16-deep register prefetch, no
// in-loop stores (states kept in regs, written at 64-step group ends).
__global__ __launch_bounds__(64) void k2_scan(const float* __restrict__ consts,
                                              float* __restrict__ states,
                                              const float* __restrict__ p_att,
                                              const float* __restrict__ p_rel) {
  const int r = blockIdx.x;
  const int lane = threadIdx.x;
  const float A = p_att[0], R = p_rel[0];
  float s = 1.f, sA = 1.f;
  for (int i = 0; i < 64; ++i) {
    s *= (i < lane) ? A : R;  // s = A^lane * R^(64-lane)
    sA *= A;                  // A^64
  }
  const bool last = (lane == 63);
  const float s2 = last ? sA : s;
  const int off1 = lane;
  const int off2 = last ? 64 : lane;
  const float* base = consts + (size_t)r * NB * NCLS;
  float* st = states + r * NB;
  float p = 0.f;

  float cb[PF], eb[PF];
#pragma unroll
  for (int u = 0; u < PF; ++u) {
    cb[u] = base[u * NCLS + off1];
    eb[u] = base[u * NCLS + off2];
  }

  for (int j = 0; j < 8; ++j) {       // 8 groups of 64 steps
    float sj = 0.f;                   // state slot: lane i holds block j*64+i
    for (int k = 0; k < 4; ++k) {     // 4 sub-groups of 16
#pragma unroll
      for (int u = 0; u < PF; ++u) {  // circular prefetch slot = u
        const int b = j * 64 + k * PF + u;
        const int i = k * PF + u;  // step within group (uniform)
        float f = fmaf(s, p, cb[u]);
        float e = fmaf(s2, p, eb[u]);
        float v = fminf(f, e);
        v = fmin_dpp_step<0x111, 0xf>(v);  // row_shr:1
        v = fmin_dpp_step<0x112, 0xf>(v);  // row_shr:2
        v = fmin_dpp_step<0x114, 0xf>(v);  // row_shr:4
        v = fmin_dpp_step<0x118, 0xf>(v);  // row_shr:8
        v = fmin_dpp_step<0x142, 0xa>(v);  // row_bcast:15
        v = fmin_dpp_step<0x143, 0xc>(v);  // row_bcast:31
        sj = (lane == i) ? p : sj;  // state at START of block b (old p)
        p = __int_as_float(
            __builtin_amdgcn_readlane(__float_as_int(v), 63));
        // refill slot u for block b+PF (buffer padded; no tail branch)
        cb[u] = base[(b + PF) * NCLS + off1];
        eb[u] = base[(b + PF) * NCLS + off2];
      }
    }
    st[j * 64 + lane] = sj;
  }
}

// K3: one wave per block. Each lane owns one frame (16 samples in regs),
// wave re-runs the 64-step recurrence from the block-start state via
// readlane broadcasts, then applies gain.
__global__ __launch_bounds__(256) void k3_apply(
    const float* __restrict__ audio, const float* __restrict__ states,
    const float* __restrict__ p_thr, const float* __restrict__ p_ratio,
    const float* __restrict__ p_makeup, const float* __restrict__ p_att,
    const float* __restrict__ p_rel, float* __restrict__ out) {
  const int tid = threadIdx.x;
  const int lane = tid & 63;
  const int w = tid >> 6;
  const int gblk = blockIdx.x * 4 + w;  // 0..32767
  const int row = gblk >> 9;
  const int b = gblk & (NB - 1);
  const float thr = p_thr[0], ratio = p_ratio[0], mk = p_makeup[0];
  const float A = p_att[0], R = p_rel[0];
  const float oneA = 1.f - A, oneR = 1.f - R;
  const float gslope = (1.f / ratio) - 1.f;

  const size_t sbase = (size_t)row * T_DIM + (size_t)(b * LBLK + lane) * D_FAC;
  const float4* ap = (const float4*)(audio + sbase);
  float4 x0 = ap[0], x1 = ap[1], x2 = ap[2], x3 = ap[3];
  float s = sum_log2_4(x0) + sum_log2_4(x1) + sum_log2_4(x2) + sum_log2_4(x3);
  float xdb = s * (DB_PER_LOG2 / 16.f);
  float g = fminf(0.f, (xdb - thr) * gslope);

  float p = states[gblk];
  float m = 0.f;
  int gi = __float_as_int(g);
#pragma unroll
  for (int t = 0; t < LBLK; ++t) {
    float gt = __int_as_float(__builtin_amdgcn_readlane(gi, t));
    p = fminf(fmaf(A, p, oneA * gt), fmaf(R, p, oneR * gt));
    m = (lane == t) ? p : m;
  }
  float mult = exp2f((m + mk) * L2TEN_OVER20);
  float4* op = (float4*)(out + sbase);
  float4 y0, y1, y2, y3;
  y0.x = x0.x * mult; y0.y = x0.y * mult; y0.z = x0.z * mult; y0.w = x0.w * mult;
  y1.x = x1.x * mult; y1.y = x1.y * mult; y1.z = x1.z * mult; y1.w = x1.w * mult;
  y2.x = x2.x * mult; y2.y = x2.y * mult; y2.z = x2.z * mult; y2.w = x2.w * mult;
  y3.x = x3.x * mult; y3.y = x3.y * mult; y3.z = x3.z * mult; y3.w = x3.w * mult;
  op[0] = y0; op[1] = y1; op[2] = y2; op[3] = y3;
}

extern "C" void kernel_launch(void* const* d_in, const int* in_sizes, int n_in,
                              void* d_out, int out_size, void* d_ws,
                              size_t ws_size, hipStream_t stream) {
  const float* audio = (const float*)d_in[0];
  const float* thr = (const float*)d_in[1];
  const float* ratio = (const float*)d_in[2];
  const float* makeup = (const float*)d_in[3];
  const float* att = (const float*)d_in[4];
  const float* rel = (const float*)d_in[5];
  float* out = (float*)d_out;

  const size_t CONSTS_BYTES = (size_t)B_DIM * NB * NCLS * sizeof(float);  // ~8.5 MB
  const size_t PAD_BYTES = (size_t)PF * NCLS * sizeof(float);             // tail prefetch pad
  const size_t STATES_BYTES = (size_t)B_DIM * NB * sizeof(float);         // 128 KB

  float* consts;
  float* states;
  if (ws_size >= CONSTS_BYTES + PAD_BYTES + STATES_BYTES) {
    consts = (float*)d_ws;
    states = (float*)((char*)d_ws + CONSTS_BYTES + PAD_BYTES);
  } else {
    // d_out (128 MB) as scratch for consts: only live during K1->K2, and K3
    // overwrites every byte of d_out afterwards. states (128 KB) in ws.
    consts = (float*)d_out;
    states = (float*)d_ws;
  }

  hipLaunchKernelGGL(k1_compose, dim3(512), dim3(256), 0, stream, audio, thr,
                     ratio, att, rel, consts);
  hipLaunchKernelGGL(k2_scan, dim3(64), dim3(64), 0, stream, consts, states,
                     att, rel);
  hipLaunchKernelGGL(k3_apply, dim3(8192), dim3(256), 0, stream, audio, states,
                     thr, ratio, makeup, att, rel, out);
}